// Round 3
// baseline (276.224 us; speedup 1.0000x reference)
//
#include <hip/hip_runtime.h>
#include <math.h>

#define BB 16
#define NN 8192
#define MM 64
#define ROW 85
#define EPS_F 1e-7f

#define NT1 256          // prep block
#define NT2 1024         // nms block
#define PT1 (NN / NT2)   // 8 boxes/thread, bulk phase
#define CAP 3072         // sparse-phase capacity
#define PT2 (CAP / NT2)  // 3 boxes/thread, sparse phase
#define NW  (NT2 / 64)   // 16 waves

// ---------------- Kernel 1: boxes + masked score keys ----------------
__global__ void prep_kernel(const float* __restrict__ outp,
                            const float* __restrict__ lab,
                            float4* __restrict__ boxes,
                            float* __restrict__ keys) {
    __shared__ float4 gbox[MM];
    __shared__ float garea[MM];
    const int b = blockIdx.x;
    const int tid = threadIdx.x;
    if (tid < MM) {
        const float* lr = lab + ((size_t)b * MM + tid) * 5;
        float cx = lr[1], cy = lr[2], w = lr[3], h = lr[4];
        float x1 = fminf(fmaxf(cx - w * 0.5f, 0.f), 1.f) * 640.f;
        float y1 = fminf(fmaxf(cy - h * 0.5f, 0.f), 1.f) * 640.f;
        float x2 = fminf(fmaxf(cx + w * 0.5f, 0.f), 1.f) * 640.f;
        float y2 = fminf(fmaxf(cy + h * 0.5f, 0.f), 1.f) * 640.f;
        gbox[tid] = make_float4(x1, y1, x2, y2);
        garea[tid] = (x2 - x1) * (y2 - y1);
    }
    __syncthreads();
    const int n = blockIdx.y * NT1 + tid;
    const float* row = outp + ((size_t)b * NN + n) * ROW;
    float cx = row[0], cy = row[1], w = row[2], h = row[3];
    float obj = row[4], c0 = row[5];
    float px1 = cx - w * 0.5f, py1 = cy - h * 0.5f;
    float px2 = cx + w * 0.5f, py2 = cy + h * 0.5f;
    float pa = (px2 - px1) * (py2 - py1);

    const int m0 = n & (MM - 1);       // pred n's own GT: almost always matches
    bool match;
    {
        float4 g = gbox[m0];
        float iw = fmaxf(fminf(px2, g.z) - fmaxf(px1, g.x), 0.f);
        float ih = fmaxf(fminf(py2, g.w) - fmaxf(py1, g.y), 0.f);
        float inter = iw * ih;
        match = (inter / (garea[m0] + pa - inter) >= 0.5f);  // exact div as reference
    }
    if (!match) {
        for (int m = 0; m < MM; ++m) {
            float4 g = gbox[m];
            float iw = fmaxf(fminf(px2, g.z) - fmaxf(px1, g.x), 0.f);
            float ih = fmaxf(fminf(py2, g.w) - fmaxf(py1, g.y), 0.f);
            float inter = iw * ih;
            match = match || (inter / (garea[m] + pa - inter) >= 0.5f);
        }
    }
    bool valid = (obj >= 0.0f) && match;
    size_t bn = (size_t)b * NN + n;
    boxes[bn] = make_float4(px1, py1, px2, py2);
    keys[bn] = valid ? (c0 * obj) : -INFINITY;
}

// ---------------- NMS helpers ----------------
// wave64 max via DPP (6 VALU steps), result broadcast via readlane(63)
__device__ __forceinline__ float wave_max64(float x) {
#define DPP_STEP(ctrl)                                                           \
    { int _o = __builtin_amdgcn_update_dpp(__float_as_int(x), __float_as_int(x), \
                                           (ctrl), 0xF, 0xF, false);             \
      x = fmaxf(x, __int_as_float(_o)); }
    DPP_STEP(0x111);  // row_shr:1
    DPP_STEP(0x112);  // row_shr:2
    DPP_STEP(0x114);  // row_shr:4
    DPP_STEP(0x118);  // row_shr:8
    DPP_STEP(0x142);  // row_bcast:15
    DPP_STEP(0x143);  // row_bcast:31
#undef DPP_STEP
    return __int_as_float(__builtin_amdgcn_readlane(__float_as_int(x), 63));
}

template <int PT>
__device__ __forceinline__ void publish(float (&x1)[PT], float (&y1)[PT],
                                        float (&x2)[PT], float (&y2)[PT],
                                        float (&ar)[PT], float lv, int la,
                                        float (*pub)[NW][8], int p,
                                        int tid, int wid, int lane) {
    float wmax = wave_max64(lv);
    unsigned long long mask = __ballot(lv == wmax);
    int winLane = __ffsll((unsigned long long)mask) - 1;
    if (lane == winLane) {
        float bx1 = x1[0], by1 = y1[0], bx2 = x2[0], by2 = y2[0], ba = ar[0];
#pragma unroll
        for (int k = 1; k < PT; ++k)
            if (la == k) { bx1 = x1[k]; by1 = y1[k]; bx2 = x2[k]; by2 = y2[k]; ba = ar[k]; }
        pub[p][wid][0] = lv;            // == wmax on this lane
        pub[p][wid][1] = (float)tid;
        pub[p][wid][2] = bx1; pub[p][wid][3] = by1;
        pub[p][wid][4] = bx2; pub[p][wid][5] = by2;
        pub[p][wid][6] = ba;
    }
}

template <int PT>
__device__ __forceinline__ void init_publish(float (&x1)[PT], float (&y1)[PT],
                                             float (&x2)[PT], float (&y2)[PT],
                                             float (&ar)[PT], float (&sc)[PT],
                                             int &myLa, float (*pub)[NW][8], int p,
                                             int tid, int wid, int lane) {
    float lv = -INFINITY; int la = 0;
#pragma unroll
    for (int k = 0; k < PT; ++k)
        if (sc[k] > lv) { lv = sc[k]; la = k; }
    myLa = la;
    publish<PT>(x1, y1, x2, y2, ar, lv, la, pub, p, tid, wid, lane);
    __syncthreads();
}

// one selection round; returns false when no live box remains
template <int PT>
__device__ __forceinline__ bool do_round(float (&x1)[PT], float (&y1)[PT],
                                         float (&x2)[PT], float (&y2)[PT],
                                         float (&ar)[PT], float (&sc)[PT],
                                         int &myLa, float (*pub)[NW][8], int &p,
                                         float &sum, int &cnt,
                                         int tid, int wid, int lane) {
    float gv = -INFINITY; int gw = 0;
#pragma unroll
    for (int w = 0; w < NW; ++w) {
        float v = pub[p][w][0];
        if (v > gv) { gv = v; gw = w; }
    }
    if (gv == -INFINITY) return false;     // uniform exit
    sum += gv; cnt++;
    int   gtid  = (int)pub[p][gw][1];
    float cx1   = pub[p][gw][2], cy1 = pub[p][gw][3];
    float cx2   = pub[p][gw][4], cy2 = pub[p][gw][5];
    float carea = pub[p][gw][6];
    bool winner = (tid == gtid);

    float lv = -INFINITY; int la = 0;
#pragma unroll
    for (int k = 0; k < PT; ++k) {
        float v = sc[k];
        if (v != -INFINITY) {
            if (winner && k == myLa) {
                v = -INFINITY;             // remove selected box
            } else {
                float xx1 = fmaxf(cx1, x1[k]), yy1 = fmaxf(cy1, y1[k]);
                float xx2 = fminf(cx2, x2[k]), yy2 = fminf(cy2, y2[k]);
                float iw = fmaxf(xx2 - xx1 + 1.f, 0.f);
                float ih = fmaxf(yy2 - yy1 + 1.f, 0.f);
                float inter = iw * ih;
                // iou > 0.5  <=>  inter > 0.5*(A+B-inter+EPS)   (union > 0)
                if (inter > 0.5f * (carea + ar[k] - inter + EPS_F)) v = -INFINITY;
            }
            sc[k] = v;
        }
        if (v > lv) { lv = v; la = k; }
    }
    myLa = la;
    int np = p ^ 1;
    publish<PT>(x1, y1, x2, y2, ar, lv, la, pub, np, tid, wid, lane);
    __syncthreads();
    p = np;
    return true;
}

// ---------------- Kernel 2: two-phase register/LDS NMS ----------------
__global__ void __launch_bounds__(NT2, 4)
nms_kernel(const float4* __restrict__ boxes, const float* __restrict__ keys,
           float* __restrict__ loss) {
    __shared__ float pub[2][NW][8];
    __shared__ int liveCnt[NW];
    __shared__ float sx1[CAP], sy1[CAP], sx2[CAP], sy2[CAP], ssc[CAP];  // 60 KB

    const int b = blockIdx.x;
    const int tid = threadIdx.x;
    const int wid = tid >> 6;
    const int lane = tid & 63;
    const size_t base = (size_t)b * NN;

    float ex1[PT1], ey1[PT1], ex2[PT1], ey2[PT1], ea[PT1], es[PT1];
#pragma unroll
    for (int k = 0; k < PT1; ++k) {
        int n = k * NT2 + tid;                 // coalesced
        float4 bb = boxes[base + n];
        ex1[k] = bb.x; ey1[k] = bb.y; ex2[k] = bb.z; ey2[k] = bb.w;
        es[k] = keys[base + n];
        ea[k] = (ex2[k] - ex1[k] + 1.f) * (ey2[k] - ey1[k] + 1.f);
    }

    int myLa, p = 0;
    float sum = 0.f; int cnt = 0;
    init_publish<PT1>(ex1, ey1, ex2, ey2, ea, es, myLa, pub, p, tid, wid, lane);

    int round = 0, liveTot = 0;
    bool toSparse = false;
    while (true) {
        if (!do_round<PT1>(ex1, ey1, ex2, ey2, ea, es, myLa, pub, p, sum, cnt,
                           tid, wid, lane)) break;
        if ((++round & 3) == 0) {
            int wsum = 0;
#pragma unroll
            for (int k = 0; k < PT1; ++k)
                wsum += (int)__popcll(__ballot(es[k] != -INFINITY));
            if (lane == 0) liveCnt[wid] = wsum;
            __syncthreads();
            int tot = 0;
#pragma unroll
            for (int w = 0; w < NW; ++w) tot += liveCnt[w];
            if (tot <= CAP) {
                // compact survivors into LDS at deterministic ballot-prefix slots
                int waveBase = 0;
                for (int w = 0; w < wid; ++w) waveBase += liveCnt[w];
                int kb = 0;
#pragma unroll
                for (int k = 0; k < PT1; ++k) {
                    unsigned long long m = __ballot(es[k] != -INFINITY);
                    if (es[k] != -INFINITY) {
                        int pos = waveBase + kb +
                                  (int)__popcll(m & ((1ull << lane) - 1ull));
                        sx1[pos] = ex1[k]; sy1[pos] = ey1[k];
                        sx2[pos] = ex2[k]; sy2[pos] = ey2[k];
                        ssc[pos] = es[k];
                    }
                    kb += (int)__popcll(m);
                }
                liveTot = tot;
                toSparse = true;
                __syncthreads();
                break;
            }
            // no barrier needed: next liveCnt write is >=1 round-barrier away
        }
    }

    if (toSparse) {
        float fx1[PT2], fy1[PT2], fx2[PT2], fy2[PT2], fa[PT2], fs[PT2];
#pragma unroll
        for (int q = 0; q < PT2; ++q) {
            int i = q * NT2 + tid;
            bool in = (i < liveTot);
            fx1[q] = in ? sx1[i] : 0.f;
            fy1[q] = in ? sy1[i] : 0.f;
            fx2[q] = in ? sx2[i] : 0.f;
            fy2[q] = in ? sy2[i] : 0.f;
            fs[q]  = in ? ssc[i] : -INFINITY;
            fa[q] = (fx2[q] - fx1[q] + 1.f) * (fy2[q] - fy1[q] + 1.f);  // bit-identical
        }
        init_publish<PT2>(fx1, fy1, fx2, fy2, fa, fs, myLa, pub, p, tid, wid, lane);
        while (do_round<PT2>(fx1, fy1, fx2, fy2, fa, fs, myLa, pub, p, sum, cnt,
                             tid, wid, lane)) {}
    }

    if (tid == 0) loss[b] = sum / (float)cnt;   // 0/0 -> NaN matches reference
}

extern "C" void kernel_launch(void* const* d_in, const int* in_sizes, int n_in,
                              void* d_out, int out_size, void* d_ws, size_t ws_size,
                              hipStream_t stream) {
    const float* outp = (const float*)d_in[0];   // (B, N, 85) f32
    const float* lab  = (const float*)d_in[1];   // (B, M, 5)  f32
    float* loss = (float*)d_out;                 // (1, B) f32

    float4* boxes = (float4*)d_ws;                                    // 2 MB
    float*  keys  = (float*)((char*)d_ws + (size_t)BB * NN * sizeof(float4));

    dim3 g1(BB, NN / NT1);
    prep_kernel<<<g1, NT1, 0, stream>>>(outp, lab, boxes, keys);
    nms_kernel<<<BB, NT2, 0, stream>>>(boxes, keys, loss);
}

// Round 4
// 132.263 us; speedup vs baseline: 2.0884x; 2.0884x over previous
//
#include <hip/hip_runtime.h>
#include <math.h>

#define BB 16
#define NN 8192
#define MM 64
#define ROW 85
#define EPS_F 1e-7f

#define NT1 256          // prep block
#define NT2 1024         // nms block
#define PT1 8            // bulk slots/thread
#define NW  (NT2 / 64)   // 16 waves
#define THR1 4096        // compact -> 4 slots
#define THR2 2048        // compact -> 2 slots

// ---------------- Kernel 1: boxes + masked score keys ----------------
__global__ void prep_kernel(const float* __restrict__ outp,
                            const float* __restrict__ lab,
                            float4* __restrict__ boxes,
                            float* __restrict__ keys) {
    __shared__ float4 gbox[MM];
    __shared__ float garea[MM];
    const int b = blockIdx.x;
    const int tid = threadIdx.x;
    if (tid < MM) {
        const float* lr = lab + ((size_t)b * MM + tid) * 5;
        float cx = lr[1], cy = lr[2], w = lr[3], h = lr[4];
        float x1 = fminf(fmaxf(cx - w * 0.5f, 0.f), 1.f) * 640.f;
        float y1 = fminf(fmaxf(cy - h * 0.5f, 0.f), 1.f) * 640.f;
        float x2 = fminf(fmaxf(cx + w * 0.5f, 0.f), 1.f) * 640.f;
        float y2 = fminf(fmaxf(cy + h * 0.5f, 0.f), 1.f) * 640.f;
        gbox[tid] = make_float4(x1, y1, x2, y2);
        garea[tid] = (x2 - x1) * (y2 - y1);
    }
    __syncthreads();
    const int n = blockIdx.y * NT1 + tid;
    const float* row = outp + ((size_t)b * NN + n) * ROW;
    float cx = row[0], cy = row[1], w = row[2], h = row[3];
    float obj = row[4], c0 = row[5];
    float px1 = cx - w * 0.5f, py1 = cy - h * 0.5f;
    float px2 = cx + w * 0.5f, py2 = cy + h * 0.5f;
    float pa = (px2 - px1) * (py2 - py1);

    const int m0 = n & (MM - 1);       // pred n's own GT: almost always matches
    bool match;
    {
        float4 g = gbox[m0];
        float iw = fmaxf(fminf(px2, g.z) - fmaxf(px1, g.x), 0.f);
        float ih = fmaxf(fminf(py2, g.w) - fmaxf(py1, g.y), 0.f);
        float inter = iw * ih;
        match = (inter / (garea[m0] + pa - inter) >= 0.5f);  // exact div as reference
    }
    if (!match) {
        for (int m = 0; m < MM; ++m) {
            float4 g = gbox[m];
            float iw = fmaxf(fminf(px2, g.z) - fmaxf(px1, g.x), 0.f);
            float ih = fmaxf(fminf(py2, g.w) - fmaxf(py1, g.y), 0.f);
            float inter = iw * ih;
            match = match || (inter / (garea[m] + pa - inter) >= 0.5f);
        }
    }
    bool valid = (obj >= 0.0f) && match;
    size_t bn = (size_t)b * NN + n;
    boxes[bn] = make_float4(px1, py1, px2, py2);
    keys[bn] = valid ? (c0 * obj) : -INFINITY;
}

// wave64 max via DPP (6 VALU steps) -> broadcast from lane 63
__device__ __forceinline__ float wave_max64(float x) {
#define DPP_STEP(ctrl)                                                           \
    { int _o = __builtin_amdgcn_update_dpp(__float_as_int(x), __float_as_int(x), \
                                           (ctrl), 0xF, 0xF, false);             \
      x = fmaxf(x, __int_as_float(_o)); }
    DPP_STEP(0x111)   // row_shr:1
    DPP_STEP(0x112)   // row_shr:2
    DPP_STEP(0x114)   // row_shr:4
    DPP_STEP(0x118)   // row_shr:8
    DPP_STEP(0x142)   // row_bcast:15
    DPP_STEP(0x143)   // row_bcast:31
#undef DPP_STEP
    return __int_as_float(__builtin_amdgcn_readlane(__float_as_int(x), 63));
}

// ---- macros on locally-declared arrays (keeps R2-style codegen; no refs) ----
#define PUBLISH(PT, X1, Y1, X2, Y2, HA, LV, LA, NP) do {                       \
    float _wmax = wave_max64(LV);                                              \
    unsigned long long _m = __ballot((LV) == _wmax);                           \
    int _winLane = __ffsll(_m) - 1;                                            \
    if (lane == _winLane) {                                                    \
        float _bx1 = X1[0], _by1 = Y1[0], _bx2 = X2[0], _by2 = Y2[0], _bh = HA[0]; \
        _Pragma("unroll")                                                      \
        for (int _k = 1; _k < (PT); ++_k)                                      \
            if ((LA) == _k) { _bx1 = X1[_k]; _by1 = Y1[_k]; _bx2 = X2[_k];     \
                              _by2 = Y2[_k]; _bh = HA[_k]; }                   \
        ((float*)pubS4[NP])[wid] = (LV);                                       \
        pubT[NP][wid] = tid;                                                   \
        pubB[NP][wid] = make_float4(_bx1, _by1, _bx2, _by2);                   \
        pubHA[NP][wid] = _bh;                                                  \
    }                                                                          \
} while (0)

#define INIT_PUBLISH(PT, X1, Y1, X2, Y2, HA, SC, MYLA) do {                    \
    float _lv = -INFINITY; int _la = 0;                                        \
    _Pragma("unroll")                                                          \
    for (int _k = 0; _k < (PT); ++_k)                                          \
        if (SC[_k] > _lv) { _lv = SC[_k]; _la = _k; }                          \
    (MYLA) = _la;                                                              \
    PUBLISH(PT, X1, Y1, X2, Y2, HA, _lv, _la, p);                              \
    __syncthreads();                                                           \
} while (0)

#define CHKW(VAL, IDX) if ((VAL) > gv) { gv = (VAL); gw = (IDX); }

#define DO_ROUND(PT, X1, Y1, X2, Y2, HA, SC, MYLA) do {                        \
    float4 _sa = pubS4[p][0], _sb = pubS4[p][1];                               \
    float4 _sc2 = pubS4[p][2], _sd = pubS4[p][3];                              \
    float gv = _sa.x; int gw = 0;                                              \
    CHKW(_sa.y, 1)  CHKW(_sa.z, 2)  CHKW(_sa.w, 3)                             \
    CHKW(_sb.x, 4)  CHKW(_sb.y, 5)  CHKW(_sb.z, 6)  CHKW(_sb.w, 7)             \
    CHKW(_sc2.x, 8) CHKW(_sc2.y, 9) CHKW(_sc2.z,10) CHKW(_sc2.w,11)            \
    CHKW(_sd.x,12)  CHKW(_sd.y,13)  CHKW(_sd.z,14)  CHKW(_sd.w,15)             \
    if (gv == -INFINITY) { alive = false; }                                    \
    else {                                                                     \
        sum += gv; cnt++;                                                      \
        int _gtid = pubT[p][gw];                                               \
        float4 _cb = pubB[p][gw];                                              \
        float _hca = pubHA[p][gw] + 0.5f * EPS_F;                              \
        bool _winner = (tid == _gtid);                                         \
        float _lv = -INFINITY; int _la = 0;                                    \
        _Pragma("unroll")                                                      \
        for (int _k = 0; _k < (PT); ++_k) {                                    \
            float _v = SC[_k];                                                 \
            if (_v != -INFINITY) {                                             \
                if (_winner && _k == (MYLA)) {                                 \
                    _v = -INFINITY;                                            \
                } else {                                                       \
                    float _xx1 = fmaxf(_cb.x, X1[_k]);                         \
                    float _yy1 = fmaxf(_cb.y, Y1[_k]);                         \
                    float _xx2 = fminf(_cb.z, X2[_k]);                         \
                    float _yy2 = fminf(_cb.w, Y2[_k]);                         \
                    float _iw = fmaxf(_xx2 - _xx1 + 1.f, 0.f);                 \
                    float _ih = fmaxf(_yy2 - _yy1 + 1.f, 0.f);                 \
                    float _in = _iw * _ih;                                     \
                    /* iou>0.5 <=> 1.5*inter > 0.5*(cA+A+EPS) */               \
                    if (1.5f * _in > _hca + HA[_k]) _v = -INFINITY;            \
                }                                                              \
                SC[_k] = _v;                                                   \
            }                                                                  \
            if (_v > _lv) { _lv = _v; _la = _k; }                              \
        }                                                                      \
        (MYLA) = _la;                                                          \
        int _np = p ^ 1;                                                       \
        PUBLISH(PT, X1, Y1, X2, Y2, HA, _lv, _la, _np);                        \
        __syncthreads();                                                       \
        p = _np;                                                               \
    }                                                                          \
} while (0)

#define COUNT_LIVE(PT, SC, TOT) do {                                           \
    int _ws = 0;                                                               \
    _Pragma("unroll")                                                          \
    for (int _k = 0; _k < (PT); ++_k)                                          \
        _ws += (int)__popcll(__ballot(SC[_k] != -INFINITY));                   \
    if (lane == 0) liveCnt[wid] = _ws;                                         \
    __syncthreads();                                                           \
    (TOT) = 0;                                                                 \
    _Pragma("unroll")                                                          \
    for (int _w = 0; _w < NW; ++_w) (TOT) += liveCnt[_w];                      \
} while (0)

#define COMPACT(PT, SC, IDX_EXPR) do {                                         \
    int _wb = 0;                                                               \
    for (int _w = 0; _w < wid; ++_w) _wb += liveCnt[_w];                       \
    int _kb = 0;                                                               \
    _Pragma("unroll")                                                          \
    for (int _k = 0; _k < (PT); ++_k) {                                        \
        unsigned long long _m = __ballot(SC[_k] != -INFINITY);                 \
        if (SC[_k] != -INFINITY) {                                             \
            int _pos = _wb + _kb + (int)__popcll(_m & ((1ull << lane) - 1ull));\
            idxLds[_pos] = (IDX_EXPR);                                         \
        }                                                                      \
        _kb += (int)__popcll(_m);                                              \
    }                                                                          \
    __syncthreads();                                                           \
} while (0)

#define REDIST(PTN, X1, Y1, X2, Y2, HA, SC, IX) do {                           \
    _Pragma("unroll")                                                          \
    for (int _q = 0; _q < (PTN); ++_q) {                                       \
        int _i = _q * NT2 + tid;                                               \
        bool _in = (_i < liveTot);                                             \
        int _n = _in ? idxLds[_i] : 0;                                         \
        float4 _bb = boxes[base + _n];                                         \
        X1[_q] = _bb.x; Y1[_q] = _bb.y; X2[_q] = _bb.z; Y2[_q] = _bb.w;        \
        SC[_q] = _in ? keys[base + _n] : -INFINITY;                            \
        HA[_q] = 0.5f * ((X2[_q] - X1[_q] + 1.f) * (Y2[_q] - Y1[_q] + 1.f));   \
        IX[_q] = _n;                                                           \
    }                                                                          \
} while (0)

// ---------------- Kernel 2: compacting register NMS ----------------
__global__ void __launch_bounds__(NT2)
nms_kernel(const float4* __restrict__ boxes, const float* __restrict__ keys,
           float* __restrict__ loss) {
    __shared__ float4 pubS4[2][4];     // 16 wave-max scores, float4-scannable
    __shared__ float4 pubB[2][NW];     // winner boxes
    __shared__ float  pubHA[2][NW];    // winner half-areas
    __shared__ int    pubT[2][NW];     // winner tids
    __shared__ int    liveCnt[NW];
    __shared__ int    idxLds[THR1];    // 16 KB compaction indices

    const int b = blockIdx.x;
    const int tid = threadIdx.x;
    const int wid = tid >> 6;
    const int lane = tid & 63;
    const size_t base = (size_t)b * NN;

    float ex1[PT1], ey1[PT1], ex2[PT1], ey2[PT1], eh[PT1], es[PT1];
#pragma unroll
    for (int k = 0; k < PT1; ++k) {
        int n = k * NT2 + tid;                 // coalesced
        float4 bb = boxes[base + n];
        ex1[k] = bb.x; ey1[k] = bb.y; ex2[k] = bb.z; ey2[k] = bb.w;
        es[k] = keys[base + n];
        eh[k] = 0.5f * ((ex2[k] - ex1[k] + 1.f) * (ey2[k] - ey1[k] + 1.f));
    }

    float sum = 0.f; int cnt = 0;
    int p = 0, myLa = 0, round = 0, liveTot = 0;
    bool alive = true;

    INIT_PUBLISH(PT1, ex1, ey1, ex2, ey2, eh, es, myLa);

    // ---- phase 0: 8 slots/thread ----
    bool compacted = false;
    while (alive) {
        DO_ROUND(PT1, ex1, ey1, ex2, ey2, eh, es, myLa);
        if (!alive) break;
        if ((++round & 3) == 0) {
            int tot; COUNT_LIVE(PT1, es, tot);
            if (tot <= THR1) {
                COMPACT(PT1, es, (_k * NT2 + tid));
                liveTot = tot; compacted = true; break;
            }
        }
    }

    if (alive && compacted) {
        // ---- phase 1: 4 slots/thread ----
        float fx1[4], fy1[4], fx2[4], fy2[4], fh[4], fs[4]; int ix4[4];
        REDIST(4, fx1, fy1, fx2, fy2, fh, fs, ix4);
        INIT_PUBLISH(4, fx1, fy1, fx2, fy2, fh, fs, myLa);
        bool compact2 = false;
        while (alive) {
            DO_ROUND(4, fx1, fy1, fx2, fy2, fh, fs, myLa);
            if (!alive) break;
            if ((++round & 3) == 0) {
                int tot; COUNT_LIVE(4, fs, tot);
                if (tot <= THR2) {
                    COMPACT(4, fs, (ix4[_k]));
                    liveTot = tot; compact2 = true; break;
                }
            }
        }
        if (alive && compact2) {
            // ---- phase 2: 2 slots/thread, run to completion ----
            float gx1[2], gy1[2], gx2[2], gy2[2], gh[2], gs[2]; int ix2[2];
            REDIST(2, gx1, gy1, gx2, gy2, gh, gs, ix2);
            (void)ix2;
            INIT_PUBLISH(2, gx1, gy1, gx2, gy2, gh, gs, myLa);
            while (alive) {
                DO_ROUND(2, gx1, gy1, gx2, gy2, gh, gs, myLa);
            }
        }
    }

    if (tid == 0) loss[b] = sum / (float)cnt;   // 0/0 -> NaN matches reference
}

extern "C" void kernel_launch(void* const* d_in, const int* in_sizes, int n_in,
                              void* d_out, int out_size, void* d_ws, size_t ws_size,
                              hipStream_t stream) {
    const float* outp = (const float*)d_in[0];   // (B, N, 85) f32
    const float* lab  = (const float*)d_in[1];   // (B, M, 5)  f32
    float* loss = (float*)d_out;                 // (1, B) f32

    float4* boxes = (float4*)d_ws;                                    // 2 MB
    float*  keys  = (float*)((char*)d_ws + (size_t)BB * NN * sizeof(float4));

    dim3 g1(BB, NN / NT1);
    prep_kernel<<<g1, NT1, 0, stream>>>(outp, lab, boxes, keys);
    nms_kernel<<<BB, NT2, 0, stream>>>(boxes, keys, loss);
}

// Round 5
// 127.016 us; speedup vs baseline: 2.1747x; 1.0413x over previous
//
#include <hip/hip_runtime.h>
#include <math.h>

#define BB 16
#define NN 8192
#define MM 64
#define ROW 85
#define EPS_F 1e-7f

#define NT1 256          // prep block
#define NT2 1024         // nms block
#define PT1 8            // head slots/thread (4 cluster-pairs)
#define NW  16           // waves
#define THR2 2048        // compact -> 2 slots tail
#define PT2 2

// ---------------- Kernel 1: boxes + masked score keys (cluster-permuted) ----------------
__global__ void prep_kernel(const float* __restrict__ outp,
                            const float* __restrict__ lab,
                            float4* __restrict__ boxes,
                            float* __restrict__ keys) {
    __shared__ float4 gbox[MM];
    __shared__ float garea[MM];
    const int b = blockIdx.x;
    const int tid = threadIdx.x;
    if (tid < MM) {
        const float* lr = lab + ((size_t)b * MM + tid) * 5;
        float cx = lr[1], cy = lr[2], w = lr[3], h = lr[4];
        float x1 = fminf(fmaxf(cx - w * 0.5f, 0.f), 1.f) * 640.f;
        float y1 = fminf(fmaxf(cy - h * 0.5f, 0.f), 1.f) * 640.f;
        float x2 = fminf(fmaxf(cx + w * 0.5f, 0.f), 1.f) * 640.f;
        float y2 = fminf(fmaxf(cy + h * 0.5f, 0.f), 1.f) * 640.f;
        gbox[tid] = make_float4(x1, y1, x2, y2);
        garea[tid] = (x2 - x1) * (y2 - y1);
    }
    __syncthreads();
    const int n = blockIdx.y * NT1 + tid;
    const float* row = outp + ((size_t)b * NN + n) * ROW;
    float cx = row[0], cy = row[1], w = row[2], h = row[3];
    float obj = row[4], c0 = row[5];
    float px1 = cx - w * 0.5f, py1 = cy - h * 0.5f;
    float px2 = cx + w * 0.5f, py2 = cy + h * 0.5f;
    float pa = (px2 - px1) * (py2 - py1);

    const int m0 = n & (MM - 1);       // pred n's own GT: almost always matches
    bool match;
    {
        float4 g = gbox[m0];
        float iw = fmaxf(fminf(px2, g.z) - fmaxf(px1, g.x), 0.f);
        float ih = fmaxf(fminf(py2, g.w) - fmaxf(py1, g.y), 0.f);
        float inter = iw * ih;
        match = (inter / (garea[m0] + pa - inter) >= 0.5f);  // exact div as reference
    }
    if (!match) {
        for (int m = 0; m < MM; ++m) {
            float4 g = gbox[m];
            float iw = fmaxf(fminf(px2, g.z) - fmaxf(px1, g.x), 0.f);
            float ih = fmaxf(fminf(py2, g.w) - fmaxf(py1, g.y), 0.f);
            float inter = iw * ih;
            match = match || (inter / (garea[m] + pa - inter) >= 0.5f);
        }
    }
    bool valid = (obj >= 0.0f) && match;
    // cluster permutation: ppos = (n%64)*128 + n/64  (pure bijection; c==true cluster ~always)
    size_t bn = (size_t)b * NN + ((n & 63) * 128 + (n >> 6));
    boxes[bn] = make_float4(px1, py1, px2, py2);
    keys[bn] = valid ? (c0 * obj) : -INFINITY;
}

// ---------------- DPP wave folds (result valid at lane 63) ----------------
__device__ __forceinline__ float wave_fold_max(float x) {
#define DPP_STEPX(ctrl)                                                          \
    { int _o = __builtin_amdgcn_update_dpp(__float_as_int(x), __float_as_int(x), \
                                           (ctrl), 0xF, 0xF, false);             \
      x = fmaxf(x, __int_as_float(_o)); }
    DPP_STEPX(0x111) DPP_STEPX(0x112) DPP_STEPX(0x114)
    DPP_STEPX(0x118) DPP_STEPX(0x142) DPP_STEPX(0x143)
#undef DPP_STEPX
    return x;
}
__device__ __forceinline__ float wave_fold_min(float x) {
#define DPP_STEPN(ctrl)                                                          \
    { int _o = __builtin_amdgcn_update_dpp(__float_as_int(x), __float_as_int(x), \
                                           (ctrl), 0xF, 0xF, false);             \
      x = fminf(x, __int_as_float(_o)); }
    DPP_STEPN(0x111) DPP_STEPN(0x112) DPP_STEPN(0x114)
    DPP_STEPN(0x118) DPP_STEPN(0x142) DPP_STEPN(0x143)
#undef DPP_STEPN
    return x;
}
__device__ __forceinline__ float wave_max64(float x) {
    return __int_as_float(__builtin_amdgcn_readlane(__float_as_int(wave_fold_max(x)), 63));
}

// pack wave id into score low bits (<=15 ulp perturbation; deterministic)
#define PACKF(LV) (((LV) == -INFINITY) ? -INFINITY :                            \
    __uint_as_float((__float_as_uint(LV) & ~15u) | (unsigned)wid))

#define OVLP(CB, B) ((fminf((CB).z,(B).z) - fmaxf((CB).x,(B).x) + 1.f > 0.f) && \
                     (fminf((CB).w,(B).w) - fmaxf((CB).y,(B).y) + 1.f > 0.f))

#define PIDX(K) (512 * wid + ((K) >> 1) * 128 + ((K) & 1) * 64 + lane)

// ---- publish: wave argmax -> pub[NP][wid] (packed score) ----
#define PUBLISH(PT, X1, Y1, X2, Y2, HA, LV, LA, NP) do {                       \
    float _wmax = wave_max64(LV);                                              \
    unsigned long long _m = __ballot((LV) == _wmax);                           \
    int _winLane = __ffsll(_m) - 1;                                            \
    if (lane == _winLane) {                                                    \
        float _bx1 = X1[0], _by1 = Y1[0], _bx2 = X2[0], _by2 = Y2[0], _bh = HA[0]; \
        _Pragma("unroll")                                                      \
        for (int _k = 1; _k < (PT); ++_k)                                      \
            if ((LA) == _k) { _bx1 = X1[_k]; _by1 = Y1[_k]; _bx2 = X2[_k];     \
                              _by2 = Y2[_k]; _bh = HA[_k]; }                   \
        ((float*)pubS4[NP])[wid] = PACKF(LV);                                  \
        pubT[NP][wid] = tid;                                                   \
        pubB[NP][wid] = make_float4(_bx1, _by1, _bx2, _by2);                   \
        pubHA[NP][wid] = _bh;                                                  \
    }                                                                          \
} while (0)

#define INIT_PUBLISH(PT, X1, Y1, X2, Y2, HA, SC, MYLA) do {                    \
    float _lv = -INFINITY; int _la = 0;                                        \
    _Pragma("unroll")                                                          \
    for (int _k = 0; _k < (PT); ++_k)                                          \
        if (SC[_k] > _lv) { _lv = SC[_k]; _la = _k; }                          \
    (MYLA) = _la;                                                              \
    PUBLISH(PT, X1, Y1, X2, Y2, HA, _lv, _la, p);                              \
    __syncthreads();                                                           \
} while (0)

#define COUNT_LIVE(PT, SC, TOT) do {                                           \
    int _ws = 0;                                                               \
    _Pragma("unroll")                                                          \
    for (int _k = 0; _k < (PT); ++_k)                                          \
        _ws += (int)__popcll(__ballot(SC[_k] != -INFINITY));                   \
    if (lane == 0) liveCnt[wid] = _ws;                                         \
    __syncthreads();                                                           \
    (TOT) = 0;                                                                 \
    _Pragma("unroll")                                                          \
    for (int _w = 0; _w < NW; ++_w) (TOT) += liveCnt[_w];                      \
} while (0)

#define COMPACT(PT, SC) do {                                                   \
    int _wb = 0;                                                               \
    for (int _w = 0; _w < wid; ++_w) _wb += liveCnt[_w];                       \
    int _kb = 0;                                                               \
    _Pragma("unroll")                                                          \
    for (int _k = 0; _k < (PT); ++_k) {                                        \
        unsigned long long _m = __ballot(SC[_k] != -INFINITY);                 \
        if (SC[_k] != -INFINITY) {                                             \
            int _pos = _wb + _kb + (int)__popcll(_m & ((1ull << lane) - 1ull));\
            idxLds[_pos] = PIDX(_k);                                           \
        }                                                                      \
        _kb += (int)__popcll(_m);                                              \
    }                                                                          \
    __syncthreads();                                                           \
} while (0)

#define REDIST(PTN, X1, Y1, X2, Y2, HA, SC) do {                               \
    _Pragma("unroll")                                                          \
    for (int _q = 0; _q < (PTN); ++_q) {                                       \
        int _i = _q * NT2 + tid;                                               \
        bool _in = (_i < liveTot);                                             \
        int _n = _in ? idxLds[_i] : 0;                                         \
        float4 _bb = boxes[base + _n];                                         \
        X1[_q] = _bb.x; Y1[_q] = _bb.y; X2[_q] = _bb.z; Y2[_q] = _bb.w;        \
        SC[_q] = _in ? keys[base + _n] : -INFINITY;                            \
        HA[_q] = 0.5f * ((X2[_q] - X1[_q] + 1.f) * (Y2[_q] - Y1[_q] + 1.f));   \
    }                                                                          \
} while (0)

#define REFRESH() do {                                                         \
    _Pragma("unroll")                                                          \
    for (int _c = 0; _c < 4; ++_c) {                                           \
        const int _k0 = 2 * _c, _k1 = 2 * _c + 1;                              \
        float _mx =  INFINITY, _my =  INFINITY, _Mx = -INFINITY, _My = -INFINITY; \
        if (es[_k0] != -INFINITY) { _mx = ex1[_k0]; _my = ey1[_k0];            \
                                    _Mx = ex2[_k0]; _My = ey2[_k0]; }          \
        if (es[_k1] != -INFINITY) { _mx = fminf(_mx, ex1[_k1]);                \
            _my = fminf(_my, ey1[_k1]); _Mx = fmaxf(_Mx, ex2[_k1]);            \
            _My = fmaxf(_My, ey2[_k1]); }                                      \
        _mx = wave_fold_min(_mx); _my = wave_fold_min(_my);                    \
        _Mx = wave_fold_max(_Mx); _My = wave_fold_max(_My);                    \
        if (lane == 63) clusterBB[4 * wid + _c] = make_float4(_mx, _my, _Mx, _My); \
    }                                                                          \
    if (lane == 0) {                                                           \
        float4 _a = clusterBB[4 * wid], _b2 = clusterBB[4 * wid + 1];          \
        float4 _c2 = clusterBB[4 * wid + 2], _d2 = clusterBB[4 * wid + 3];     \
        wbbU[wid] = make_float4(fminf(fminf(_a.x, _b2.x), fminf(_c2.x, _d2.x)),\
                                fminf(fminf(_a.y, _b2.y), fminf(_c2.y, _d2.y)),\
                                fmaxf(fmaxf(_a.z, _b2.z), fmaxf(_c2.z, _d2.z)),\
                                fmaxf(fmaxf(_a.w, _b2.w), fmaxf(_c2.w, _d2.w)));\
    }                                                                          \
} while (0)

#define SUPSLOT(K, HK) {                                                       \
    float _v = es[K];                                                          \
    if ((HK) && _v != -INFINITY) {                                             \
        if (winner && (K) == myLa) _v = -INFINITY;                             \
        else {                                                                 \
            float _xx1 = fmaxf(cb.x, ex1[K]), _yy1 = fmaxf(cb.y, ey1[K]);      \
            float _xx2 = fminf(cb.z, ex2[K]), _yy2 = fminf(cb.w, ey2[K]);      \
            float _iw = fmaxf(_xx2 - _xx1 + 1.f, 0.f);                         \
            float _ih = fmaxf(_yy2 - _yy1 + 1.f, 0.f);                         \
            float _in = _iw * _ih;                                             \
            if (1.5f * _in > hca + eh[K]) _v = -INFINITY;                      \
        }                                                                      \
        es[K] = _v;                                                            \
    }                                                                          \
    if (_v > lv) { lv = _v; la = K; }                                          \
}

// ---------------- Kernel 2: cluster-slotted wake/sleep NMS ----------------
__global__ void __launch_bounds__(NT2)
nms_kernel(const float4* __restrict__ boxes, const float* __restrict__ keys,
           float* __restrict__ loss) {
    __shared__ float4 pubS4[2][4];      // 16 packed wave-max scores
    __shared__ float4 pubB[2][NW];
    __shared__ float  pubHA[2][NW];
    __shared__ int    pubT[2][NW];
    __shared__ float4 clusterBB[64];
    __shared__ float4 wbbU[NW];
    __shared__ int    liveCnt[NW];
    __shared__ int    idxLds[THR2];     // 8 KB

    const int b = blockIdx.x;
    const int tid = threadIdx.x;
    const int wid = tid >> 6;
    const int lane = tid & 63;
    const size_t base = (size_t)b * NN;

    // slot k of (wid,lane): permuted idx = 512*wid + (k>>1)*128 + (k&1)*64 + lane (coalesced)
    float ex1[PT1], ey1[PT1], ex2[PT1], ey2[PT1], eh[PT1], es[PT1];
#pragma unroll
    for (int k = 0; k < PT1; ++k) {
        int n = PIDX(k);
        float4 bb = boxes[base + n];
        ex1[k] = bb.x; ey1[k] = bb.y; ex2[k] = bb.z; ey2[k] = bb.w;
        es[k] = keys[base + n];
        eh[k] = 0.5f * ((ex2[k] - ex1[k] + 1.f) * (ey2[k] - ey1[k] + 1.f));
    }

    float sum = 0.f; int cnt = 0;
    int p = 0, myLa = 0, round = 0, liveTot = 0;
    bool alive = true, toTail = false;

    INIT_PUBLISH(PT1, ex1, ey1, ex2, ey2, eh, es, myLa);

    // ---- head: wake/sleep rounds ----
    while (true) {
        if ((round & 15) == 0) REFRESH();

        // packed scan of 16 wave entries
        float4 sa = pubS4[p][0], sb = pubS4[p][1], sc2 = pubS4[p][2], sd = pubS4[p][3];
        float h0 = fmaxf(fmaxf(sa.x, sa.y), fmaxf(sa.z, sa.w));
        float h1 = fmaxf(fmaxf(sb.x, sb.y), fmaxf(sb.z, sb.w));
        float h2 = fmaxf(fmaxf(sc2.x, sc2.y), fmaxf(sc2.z, sc2.w));
        float h3 = fmaxf(fmaxf(sd.x, sd.y), fmaxf(sd.z, sd.w));
        float gv = fmaxf(fmaxf(h0, h1), fmaxf(h2, h3));
        if (gv == -INFINITY) { alive = false; break; }
        sum += gv; cnt++;
        int gw = (int)(__float_as_uint(gv) & 15u);
        int gtid = pubT[p][gw];
        float4 cb = pubB[p][gw];
        float hca = pubHA[p][gw] + 0.5f * EPS_F;

        int np = p ^ 1;
        float4 u = wbbU[wid];
        bool hitU = OVLP(cb, u) || ((gtid >> 6) == wid);   // wave-uniform
        if (hitU) {
            bool winner = (tid == gtid);
            float4 c0b = clusterBB[4 * wid + 0];
            float4 c1b = clusterBB[4 * wid + 1];
            float4 c2b = clusterBB[4 * wid + 2];
            float4 c3b = clusterBB[4 * wid + 3];
            bool hh0 = OVLP(cb, c0b), hh1 = OVLP(cb, c1b);
            bool hh2 = OVLP(cb, c2b), hh3 = OVLP(cb, c3b);
            float lv = -INFINITY; int la = 0;
            SUPSLOT(0, hh0) SUPSLOT(1, hh0)
            SUPSLOT(2, hh1) SUPSLOT(3, hh1)
            SUPSLOT(4, hh2) SUPSLOT(5, hh2)
            SUPSLOT(6, hh3) SUPSLOT(7, hh3)
            myLa = la;
            PUBLISH(PT1, ex1, ey1, ex2, ey2, eh, lv, la, np);
        } else if (lane == 0) {         // sleep: republish cached entry
            ((float*)pubS4[np])[wid] = ((float*)pubS4[p])[wid];
            pubB[np][wid] = pubB[p][wid];
            pubHA[np][wid] = pubHA[p][wid];
            pubT[np][wid] = pubT[p][wid];
        }
        __syncthreads();
        p = np;

        if (((++round) & 7) == 0) {
            int tot; COUNT_LIVE(PT1, es, tot);
            if (tot <= THR2) { COMPACT(PT1, es); liveTot = tot; toTail = true; break; }
        }
    }

    // ---- tail: compacted PT=2, plain rounds ----
    if (alive && toTail) {
        float fx1[PT2], fy1[PT2], fx2[PT2], fy2[PT2], fh[PT2], fs[PT2];
        REDIST(PT2, fx1, fy1, fx2, fy2, fh, fs);
        INIT_PUBLISH(PT2, fx1, fy1, fx2, fy2, fh, fs, myLa);
        while (true) {
            float4 sa = pubS4[p][0], sb = pubS4[p][1], sc2 = pubS4[p][2], sd = pubS4[p][3];
            float h0 = fmaxf(fmaxf(sa.x, sa.y), fmaxf(sa.z, sa.w));
            float h1 = fmaxf(fmaxf(sb.x, sb.y), fmaxf(sb.z, sb.w));
            float h2 = fmaxf(fmaxf(sc2.x, sc2.y), fmaxf(sc2.z, sc2.w));
            float h3 = fmaxf(fmaxf(sd.x, sd.y), fmaxf(sd.z, sd.w));
            float gv = fmaxf(fmaxf(h0, h1), fmaxf(h2, h3));
            if (gv == -INFINITY) break;
            sum += gv; cnt++;
            int gw = (int)(__float_as_uint(gv) & 15u);
            int gtid = pubT[p][gw];
            float4 cb = pubB[p][gw];
            float hca = pubHA[p][gw] + 0.5f * EPS_F;
            bool winner = (tid == gtid);
            float lv = -INFINITY; int la = 0;
#pragma unroll
            for (int k = 0; k < PT2; ++k) {
                float v = fs[k];
                if (v != -INFINITY) {
                    if (winner && k == myLa) v = -INFINITY;
                    else {
                        float xx1 = fmaxf(cb.x, fx1[k]), yy1 = fmaxf(cb.y, fy1[k]);
                        float xx2 = fminf(cb.z, fx2[k]), yy2 = fminf(cb.w, fy2[k]);
                        float iw = fmaxf(xx2 - xx1 + 1.f, 0.f);
                        float ih = fmaxf(yy2 - yy1 + 1.f, 0.f);
                        float in2 = iw * ih;
                        if (1.5f * in2 > hca + fh[k]) v = -INFINITY;
                    }
                    fs[k] = v;
                }
                if (v > lv) { lv = v; la = k; }
            }
            myLa = la;
            int np = p ^ 1;
            PUBLISH(PT2, fx1, fy1, fx2, fy2, fh, lv, la, np);
            __syncthreads();
            p = np;
        }
    }

    if (tid == 0) loss[b] = sum / (float)cnt;   // 0/0 -> NaN matches reference
}

extern "C" void kernel_launch(void* const* d_in, const int* in_sizes, int n_in,
                              void* d_out, int out_size, void* d_ws, size_t ws_size,
                              hipStream_t stream) {
    const float* outp = (const float*)d_in[0];   // (B, N, 85) f32
    const float* lab  = (const float*)d_in[1];   // (B, M, 5)  f32
    float* loss = (float*)d_out;                 // (1, B) f32

    float4* boxes = (float4*)d_ws;                                    // 2 MB
    float*  keys  = (float*)((char*)d_ws + (size_t)BB * NN * sizeof(float4));

    dim3 g1(BB, NN / NT1);
    prep_kernel<<<g1, NT1, 0, stream>>>(outp, lab, boxes, keys);
    nms_kernel<<<BB, NT2, 0, stream>>>(boxes, keys, loss);
}

// Round 6
// 108.360 us; speedup vs baseline: 2.5491x; 1.1722x over previous
//
#include <hip/hip_runtime.h>
#include <math.h>

#define BB 16
#define NN 8192
#define MM 64
#define ROW 85
#define EPS_F 1e-7f

#define NT1 256          // prep block
#define NT2 512          // nms block: 8 waves
#define NW  8
#define PT  16           // slots/thread (8 clusters per wave, 2 slots each)
#define KMAX 8           // max clusters handled per-wave; bigger comps -> block phase

// ---------------- Kernel 1: boxes + masked score keys (cluster-permuted) ----------------
__global__ void prep_kernel(const float* __restrict__ outp,
                            const float* __restrict__ lab,
                            float4* __restrict__ boxes,
                            float* __restrict__ keys) {
    __shared__ float4 gbox[MM];
    __shared__ float garea[MM];
    const int b = blockIdx.x;
    const int tid = threadIdx.x;
    if (tid < MM) {
        const float* lr = lab + ((size_t)b * MM + tid) * 5;
        float cx = lr[1], cy = lr[2], w = lr[3], h = lr[4];
        float x1 = fminf(fmaxf(cx - w * 0.5f, 0.f), 1.f) * 640.f;
        float y1 = fminf(fmaxf(cy - h * 0.5f, 0.f), 1.f) * 640.f;
        float x2 = fminf(fmaxf(cx + w * 0.5f, 0.f), 1.f) * 640.f;
        float y2 = fminf(fmaxf(cy + h * 0.5f, 0.f), 1.f) * 640.f;
        gbox[tid] = make_float4(x1, y1, x2, y2);
        garea[tid] = (x2 - x1) * (y2 - y1);
    }
    __syncthreads();
    const int n = blockIdx.y * NT1 + tid;
    const float* row = outp + ((size_t)b * NN + n) * ROW;
    float cx = row[0], cy = row[1], w = row[2], h = row[3];
    float obj = row[4], c0 = row[5];
    float px1 = cx - w * 0.5f, py1 = cy - h * 0.5f;
    float px2 = cx + w * 0.5f, py2 = cy + h * 0.5f;
    float pa = (px2 - px1) * (py2 - py1);

    const int m0 = n & (MM - 1);       // pred n's own GT: almost always matches
    bool match;
    {
        float4 g = gbox[m0];
        float iw = fmaxf(fminf(px2, g.z) - fmaxf(px1, g.x), 0.f);
        float ih = fmaxf(fminf(py2, g.w) - fmaxf(py1, g.y), 0.f);
        float inter = iw * ih;
        match = (inter / (garea[m0] + pa - inter) >= 0.5f);  // exact div as reference
    }
    if (!match) {
        for (int m = 0; m < MM; ++m) {
            float4 g = gbox[m];
            float iw = fmaxf(fminf(px2, g.z) - fmaxf(px1, g.x), 0.f);
            float ih = fmaxf(fminf(py2, g.w) - fmaxf(py1, g.y), 0.f);
            float inter = iw * ih;
            match = match || (inter / (garea[m] + pa - inter) >= 0.5f);
        }
    }
    bool valid = (obj >= 0.0f) && match;
    // cluster permutation: ppos = (n%64)*128 + n/64
    size_t bn = (size_t)b * NN + ((n & 63) * 128 + (n >> 6));
    boxes[bn] = make_float4(px1, py1, px2, py2);
    keys[bn] = valid ? (c0 * obj) : -INFINITY;
}

// ---------------- DPP wave folds (result valid at lane 63) ----------------
__device__ __forceinline__ float wave_fold_max(float x) {
#define DPP_STEPX(ctrl)                                                          \
    { int _o = __builtin_amdgcn_update_dpp(__float_as_int(x), __float_as_int(x), \
                                           (ctrl), 0xF, 0xF, false);             \
      x = fmaxf(x, __int_as_float(_o)); }
    DPP_STEPX(0x111) DPP_STEPX(0x112) DPP_STEPX(0x114)
    DPP_STEPX(0x118) DPP_STEPX(0x142) DPP_STEPX(0x143)
#undef DPP_STEPX
    return x;
}
__device__ __forceinline__ float wave_fold_min(float x) {
#define DPP_STEPN(ctrl)                                                          \
    { int _o = __builtin_amdgcn_update_dpp(__float_as_int(x), __float_as_int(x), \
                                           (ctrl), 0xF, 0xF, false);             \
      x = fminf(x, __int_as_float(_o)); }
    DPP_STEPN(0x111) DPP_STEPN(0x112) DPP_STEPN(0x114)
    DPP_STEPN(0x118) DPP_STEPN(0x142) DPP_STEPN(0x143)
#undef DPP_STEPN
    return x;
}
__device__ __forceinline__ float wave_max64(float x) {
    return __int_as_float(__builtin_amdgcn_readlane(__float_as_int(wave_fold_max(x)), 63));
}

// ---------------- Kernel 2: component-factorized NMS ----------------
__global__ void __launch_bounds__(NT2)
nms_kernel(const float4* __restrict__ boxes, const float* __restrict__ keys,
           float* __restrict__ loss) {
    __shared__ float4 clusterBB[MM];
    __shared__ float  clusterMinA[MM];
    __shared__ unsigned long long adjL[MM];
    __shared__ int    labelL[MM];
    __shared__ int    compClusters[MM * KMAX];
    __shared__ int    compSizeL[MM];
    __shared__ int    queueL[MM];
    __shared__ int    nSmallL;
    __shared__ unsigned long long bigMaskL;
    __shared__ float  waveSum[NW];
    __shared__ int    waveCnt[NW];
    __shared__ float  pubS[2][NW];
    __shared__ float4 pubB[2][NW];
    __shared__ float  pubHA[2][NW];
    __shared__ int    pubT[2][NW];

    const int b = blockIdx.x;
    const int tid = threadIdx.x;
    const int wid = tid >> 6;
    const int lane = tid & 63;
    const size_t base = (size_t)b * NN;

    // ---- step 1: per-cluster valid-bbox + min valid area (wave DPP folds) ----
    {
        float ex1[PT], ey1[PT], ex2[PT], ey2[PT], ear[PT], es[PT];
#pragma unroll
        for (int k = 0; k < PT; ++k) {
            int idx = 1024 * wid + (k >> 1) * 128 + (k & 1) * 64 + lane;
            float4 bb4 = boxes[base + idx];
            ex1[k] = bb4.x; ey1[k] = bb4.y; ex2[k] = bb4.z; ey2[k] = bb4.w;
            es[k] = keys[base + idx];
            ear[k] = (ex2[k] - ex1[k] + 1.f) * (ey2[k] - ey1[k] + 1.f);
        }
#pragma unroll
        for (int c = 0; c < 8; ++c) {
            const int k0 = 2 * c, k1 = 2 * c + 1;
            float mx = INFINITY, my = INFINITY, Mx = -INFINITY, My = -INFINITY, mA = INFINITY;
            if (es[k0] != -INFINITY) { mx = ex1[k0]; my = ey1[k0]; Mx = ex2[k0]; My = ey2[k0]; mA = ear[k0]; }
            if (es[k1] != -INFINITY) { mx = fminf(mx, ex1[k1]); my = fminf(my, ey1[k1]);
                                       Mx = fmaxf(Mx, ex2[k1]); My = fmaxf(My, ey2[k1]);
                                       mA = fminf(mA, ear[k1]); }
            mx = wave_fold_min(mx); my = wave_fold_min(my);
            Mx = wave_fold_max(Mx); My = wave_fold_max(My);
            mA = wave_fold_min(mA);
            if (lane == 63) {
                clusterBB[8 * wid + c] = make_float4(mx, my, Mx, My);
                clusterMinA[8 * wid + c] = mA;
            }
        }
    }
    __syncthreads();

    // ---- steps 2-4 (wave 0): conflict graph, components, queue ----
    if (wid == 0) {
        const int t = lane;
        float4 bbT = clusterBB[t];
        float  maT = clusterMinA[t];
        unsigned long long adj = 0ull;
        for (int j = 0; j < MM; ++j) {
            float4 bbJ = clusterBB[j];
            float  maJ = clusterMinA[j];
            float iw = fminf(bbT.z, bbJ.z) - fmaxf(bbT.x, bbJ.x) + 1.f;
            float ih = fminf(bbT.w, bbJ.w) - fmaxf(bbT.y, bbJ.y) + 1.f;
            if (j != t && iw > 0.f && ih > 0.f) {
                float I = iw * ih;
                // suppression impossible if 3I < aI+aJ  OR  2I < max(aI,aJ) for all pairs
                bool noe = (3.f * I < maT + maJ) || (2.f * I < fmaxf(maT, maJ));
                if (!noe) adj |= (1ull << j);
            }
        }
        adjL[t] = adj;
        labelL[t] = t;
        while (true) {                       // label propagation to component min
            int lbl = labelL[t];
            int nl = lbl;
            unsigned long long m = adj;
            while (m) { int j = __ffsll(m) - 1; m &= (m - 1);
                        int lj = labelL[j]; nl = nl < lj ? nl : lj; }
            bool ch = (nl < lbl);
            if (ch) labelL[t] = nl;
            if (__ballot(ch) == 0ull) break;
        }
        int myl = labelL[t];
        int pos = 0, sz = 0;
        for (int j = 0; j < MM; ++j) {
            bool same = (labelL[j] == myl);
            sz  += same ? 1 : 0;
            pos += (same && j < t) ? 1 : 0;
        }
        compSizeL[t] = sz;
        if (pos < KMAX) compClusters[myl * KMAX + pos] = t;
        unsigned long long bigM = __ballot(sz > KMAX);
        bool smallRoot = (myl == t) && (sz <= KMAX) && (maT < INFINITY);
        unsigned long long qm = __ballot(smallRoot);
        if (smallRoot) {
            int qpos = (int)__popcll(qm & ((1ull << t) - 1ull));
            queueL[qpos] = t;
        }
        if (t == 0) { nSmallL = (int)__popcll(qm); bigMaskL = bigM; }
    }
    __syncthreads();

    // ---- step 5: per-wave independent greedy on small components (no barriers) ----
    float wsum = 0.f; int wcnt = 0;
    {
        const int nSmall = nSmallL;
        for (int q = wid; q < nSmall; q += NW) {
            int root = queueL[q];
            int sz = compSizeL[root];
            float sx1[PT], sy1[PT], sx2[PT], sy2[PT], sha[PT], ssc[PT];
#pragma unroll
            for (int k = 0; k < PT; ++k) {
                const int i = k >> 1;
                bool en = (i < sz);                        // wave-uniform
                if (en) {
                    int c = compClusters[root * KMAX + i];
                    int idx = c * 128 + (k & 1) * 64 + lane;
                    float4 bb4 = boxes[base + idx];
                    sx1[k] = bb4.x; sy1[k] = bb4.y; sx2[k] = bb4.z; sy2[k] = bb4.w;
                    ssc[k] = keys[base + idx];
                    sha[k] = 0.5f * ((sx2[k] - sx1[k] + 1.f) * (sy2[k] - sy1[k] + 1.f));
                } else {
                    sx1[k] = sy1[k] = sx2[k] = sy2[k] = sha[k] = 0.f;
                    ssc[k] = -INFINITY;
                }
            }
            while (true) {
                float lv = -INFINITY; int la = 0;
#pragma unroll
                for (int k = 0; k < PT; ++k) if (ssc[k] > lv) { lv = ssc[k]; la = k; }
                float wm = wave_max64(lv);
                if (wm == -INFINITY) break;
                unsigned long long bm = __ballot(lv == wm);
                int wl = __ffsll(bm) - 1;
                float px1 = sx1[0], pyy1 = sy1[0], px2 = sx2[0], pyy2 = sy2[0], ph = sha[0];
#pragma unroll
                for (int k = 1; k < PT; ++k)
                    if (la == k) { px1 = sx1[k]; pyy1 = sy1[k]; px2 = sx2[k]; pyy2 = sy2[k]; ph = sha[k]; }
                float cbx1 = __shfl(px1, wl), cby1 = __shfl(pyy1, wl);
                float cbx2 = __shfl(px2, wl), cby2 = __shfl(pyy2, wl);
                float hca  = __shfl(ph, wl) + 0.5f * EPS_F;
                if (lane == wl) {
#pragma unroll
                    for (int k = 0; k < PT; ++k) if (k == la) ssc[k] = -INFINITY;
                }
                wsum += wm; wcnt++;
#pragma unroll
                for (int k = 0; k < PT; ++k) {
                    float v = ssc[k];
                    if (v != -INFINITY) {
                        float xx1 = fmaxf(cbx1, sx1[k]), yy1 = fmaxf(cby1, sy1[k]);
                        float xx2 = fminf(cbx2, sx2[k]), yy2 = fminf(cby2, sy2[k]);
                        float iwv = fmaxf(xx2 - xx1 + 1.f, 0.f);
                        float ihv = fmaxf(yy2 - yy1 + 1.f, 0.f);
                        float inr = iwv * ihv;
                        if (1.5f * inr > hca + sha[k]) ssc[k] = -INFINITY;   // iou>0.5
                    }
                }
            }
        }
    }
    if (lane == 0) { waveSum[wid] = wsum; waveCnt[wid] = wcnt; }
    __syncthreads();

    // ---- step 6: block-cooperative fallback for big components (rare) ----
    float bsum = 0.f; int bcnt = 0;
    if (bigMaskL != 0ull) {
        const unsigned long long bigM = bigMaskL;
        float tx1[PT], ty1[PT], tx2[PT], ty2[PT], tha[PT], tsc[PT];
#pragma unroll
        for (int k = 0; k < PT; ++k) {
            int c = 8 * wid + (k >> 1);
            int idx = 1024 * wid + (k >> 1) * 128 + (k & 1) * 64 + lane;
            float4 bb4 = boxes[base + idx];
            tx1[k] = bb4.x; ty1[k] = bb4.y; tx2[k] = bb4.z; ty2[k] = bb4.w;
            tsc[k] = ((bigM >> c) & 1ull) ? keys[base + idx] : -INFINITY;
            tha[k] = 0.5f * ((tx2[k] - tx1[k] + 1.f) * (ty2[k] - ty1[k] + 1.f));
        }
        int myLa, p = 0;
        {
            float lv = -INFINITY; int la = 0;
#pragma unroll
            for (int k = 0; k < PT; ++k) if (tsc[k] > lv) { lv = tsc[k]; la = k; }
            myLa = la;
            float wm = wave_max64(lv);
            unsigned long long bm = __ballot(lv == wm);
            int wl = __ffsll(bm) - 1;
            if (lane == wl) {
                float px1 = tx1[0], pyy1 = ty1[0], px2 = tx2[0], pyy2 = ty2[0], ph = tha[0];
#pragma unroll
                for (int k = 1; k < PT; ++k)
                    if (la == k) { px1 = tx1[k]; pyy1 = ty1[k]; px2 = tx2[k]; pyy2 = ty2[k]; ph = tha[k]; }
                pubS[0][wid] = lv; pubT[0][wid] = tid;
                pubB[0][wid] = make_float4(px1, pyy1, px2, pyy2);
                pubHA[0][wid] = ph;
            }
        }
        __syncthreads();
        while (true) {
            float gv = -INFINITY; int gw = 0;
#pragma unroll
            for (int w = 0; w < NW; ++w) { float v = pubS[p][w]; if (v > gv) { gv = v; gw = w; } }
            if (gv == -INFINITY) break;
            bsum += gv; bcnt++;
            int gtid = pubT[p][gw];
            float4 cb = pubB[p][gw];
            float hca = pubHA[p][gw] + 0.5f * EPS_F;
            bool winner = (tid == gtid);
            float lv = -INFINITY; int la = 0;
#pragma unroll
            for (int k = 0; k < PT; ++k) {
                float v = tsc[k];
                if (v != -INFINITY) {
                    if (winner && k == myLa) v = -INFINITY;
                    else {
                        float xx1 = fmaxf(cb.x, tx1[k]), yy1 = fmaxf(cb.y, ty1[k]);
                        float xx2 = fminf(cb.z, tx2[k]), yy2 = fminf(cb.w, ty2[k]);
                        float iwv = fmaxf(xx2 - xx1 + 1.f, 0.f);
                        float ihv = fmaxf(yy2 - yy1 + 1.f, 0.f);
                        float inr = iwv * ihv;
                        if (1.5f * inr > hca + tha[k]) v = -INFINITY;
                    }
                    tsc[k] = v;
                }
                if (v > lv) { lv = v; la = k; }
            }
            myLa = la;
            int np = p ^ 1;
            {
                float wm = wave_max64(lv);
                unsigned long long bm = __ballot(lv == wm);
                int wl = __ffsll(bm) - 1;
                if (lane == wl) {
                    float px1 = tx1[0], pyy1 = ty1[0], px2 = tx2[0], pyy2 = ty2[0], ph = tha[0];
#pragma unroll
                    for (int k = 1; k < PT; ++k)
                        if (la == k) { px1 = tx1[k]; pyy1 = ty1[k]; px2 = tx2[k]; pyy2 = ty2[k]; ph = tha[k]; }
                    pubS[np][wid] = lv; pubT[np][wid] = tid;
                    pubB[np][wid] = make_float4(px1, pyy1, px2, pyy2);
                    pubHA[np][wid] = ph;
                }
            }
            __syncthreads();
            p = np;
        }
    }

    // ---- step 7: final reduce ----
    if (tid == 0) {
        float tot = bsum; int ct = bcnt;
#pragma unroll
        for (int w = 0; w < NW; ++w) { tot += waveSum[w]; ct += waveCnt[w]; }
        loss[b] = tot / (float)ct;     // 0/0 -> NaN matches reference
    }
}

extern "C" void kernel_launch(void* const* d_in, const int* in_sizes, int n_in,
                              void* d_out, int out_size, void* d_ws, size_t ws_size,
                              hipStream_t stream) {
    const float* outp = (const float*)d_in[0];   // (B, N, 85) f32
    const float* lab  = (const float*)d_in[1];   // (B, M, 5)  f32
    float* loss = (float*)d_out;                 // (1, B) f32

    float4* boxes = (float4*)d_ws;                                    // 2 MB
    float*  keys  = (float*)((char*)d_ws + (size_t)BB * NN * sizeof(float4));

    dim3 g1(BB, NN / NT1);
    prep_kernel<<<g1, NT1, 0, stream>>>(outp, lab, boxes, keys);
    nms_kernel<<<BB, NT2, 0, stream>>>(boxes, keys, loss);
}

// Round 7
// 72.248 us; speedup vs baseline: 3.8232x; 1.4998x over previous
//
#include <hip/hip_runtime.h>
#include <math.h>

#define BB 16
#define NN 8192
#define MM 64
#define ROW 85
#define EPS_F 1e-7f

#define NT1 256
#define NT2 1024         // 16 waves
#define NW  16
#define CPW 4            // clusters per wave
#define CAP 128          // kept slots per cluster == cluster size -> no overflow possible

// ---------------- Kernel 1: boxes + masked score keys (cluster-permuted) ----------------
__global__ void prep_kernel(const float* __restrict__ outp,
                            const float* __restrict__ lab,
                            float4* __restrict__ boxes,
                            float* __restrict__ keys) {
    __shared__ float4 gbox[MM];
    __shared__ float garea[MM];
    const int b = blockIdx.x;
    const int tid = threadIdx.x;
    if (tid < MM) {
        const float* lr = lab + ((size_t)b * MM + tid) * 5;
        float cx = lr[1], cy = lr[2], w = lr[3], h = lr[4];
        float x1 = fminf(fmaxf(cx - w * 0.5f, 0.f), 1.f) * 640.f;
        float y1 = fminf(fmaxf(cy - h * 0.5f, 0.f), 1.f) * 640.f;
        float x2 = fminf(fmaxf(cx + w * 0.5f, 0.f), 1.f) * 640.f;
        float y2 = fminf(fmaxf(cy + h * 0.5f, 0.f), 1.f) * 640.f;
        gbox[tid] = make_float4(x1, y1, x2, y2);
        garea[tid] = (x2 - x1) * (y2 - y1);
    }
    __syncthreads();
    const int n = blockIdx.y * NT1 + tid;
    const float* row = outp + ((size_t)b * NN + n) * ROW;
    float cx = row[0], cy = row[1], w = row[2], h = row[3];
    float obj = row[4], c0 = row[5];
    float px1 = cx - w * 0.5f, py1 = cy - h * 0.5f;
    float px2 = cx + w * 0.5f, py2 = cy + h * 0.5f;
    float pa = (px2 - px1) * (py2 - py1);

    const int m0 = n & (MM - 1);
    bool match;
    {
        float4 g = gbox[m0];
        float iw = fmaxf(fminf(px2, g.z) - fmaxf(px1, g.x), 0.f);
        float ih = fmaxf(fminf(py2, g.w) - fmaxf(py1, g.y), 0.f);
        float inter = iw * ih;
        match = (inter / (garea[m0] + pa - inter) >= 0.5f);  // exact div as reference
    }
    if (!match) {
        for (int m = 0; m < MM; ++m) {
            float4 g = gbox[m];
            float iw = fmaxf(fminf(px2, g.z) - fmaxf(px1, g.x), 0.f);
            float ih = fmaxf(fminf(py2, g.w) - fmaxf(py1, g.y), 0.f);
            float inter = iw * ih;
            match = match || (inter / (garea[m] + pa - inter) >= 0.5f);
        }
    }
    bool valid = (obj >= 0.0f) && match;
    // cluster permutation: ppos = (n%64)*128 + n/64
    size_t bn = (size_t)b * NN + ((n & 63) * 128 + (n >> 6));
    boxes[bn] = make_float4(px1, py1, px2, py2);
    keys[bn] = valid ? (c0 * obj) : -INFINITY;
}

// ---------------- DPP wave folds (valid at lane 63) ----------------
__device__ __forceinline__ float wave_fold_max(float x) {
#define DPP_STEPX(ctrl)                                                          \
    { int _o = __builtin_amdgcn_update_dpp(__float_as_int(x), __float_as_int(x), \
                                           (ctrl), 0xF, 0xF, false);             \
      x = fmaxf(x, __int_as_float(_o)); }
    DPP_STEPX(0x111) DPP_STEPX(0x112) DPP_STEPX(0x114)
    DPP_STEPX(0x118) DPP_STEPX(0x142) DPP_STEPX(0x143)
#undef DPP_STEPX
    return x;
}
__device__ __forceinline__ float wave_fold_min(float x) {
#define DPP_STEPN(ctrl)                                                          \
    { int _o = __builtin_amdgcn_update_dpp(__float_as_int(x), __float_as_int(x), \
                                           (ctrl), 0xF, 0xF, false);             \
      x = fminf(x, __int_as_float(_o)); }
    DPP_STEPN(0x111) DPP_STEPN(0x112) DPP_STEPN(0x114)
    DPP_STEPN(0x118) DPP_STEPN(0x142) DPP_STEPN(0x143)
#undef DPP_STEPN
    return x;
}
__device__ __forceinline__ float wave_max64(float x) {
    return __int_as_float(__builtin_amdgcn_readlane(__float_as_int(wave_fold_max(x)), 63));
}
// wave64 sum; old=0 + bound_ctrl=true so inactive sources contribute 0 (no double count)
__device__ __forceinline__ float wave_sum64(float x) {
#define DPP_ADD(ctrl)                                                            \
    { int _o = __builtin_amdgcn_update_dpp(0, __float_as_int(x),                 \
                                           (ctrl), 0xF, 0xF, true);              \
      x += __int_as_float(_o); }
    DPP_ADD(0x111) DPP_ADD(0x112) DPP_ADD(0x114)
    DPP_ADD(0x118) DPP_ADD(0x142) DPP_ADD(0x143)
#undef DPP_ADD
    return __int_as_float(__builtin_amdgcn_readlane(__float_as_int(x), 63));
}

// ---------------- Kernel 2: Jacobi fixed-point greedy NMS ----------------
__global__ void __launch_bounds__(NT2)
nms_kernel(const float4* __restrict__ boxes, const float* __restrict__ keys,
           float* __restrict__ loss) {
    __shared__ float4 clusterBB[MM];
    __shared__ float  clusterMinA[MM];
    __shared__ unsigned long long adjL[MM];
    __shared__ short  keptIdx[2][MM][CAP];   // 32 KB
    __shared__ int    keptCnt[2][MM];
    __shared__ int    changedL[2][MM];
    __shared__ int    anyChange[2];
    __shared__ float  waveSum[NW];
    __shared__ int    waveCnt[NW];

    const int b = blockIdx.x;
    const int tid = threadIdx.x;
    const int wid = tid >> 6;
    const int lane = tid & 63;
    const size_t base = (size_t)b * NN;

    // pristine per-thread state: 4 clusters x 2 slots (static indexing via unroll)
    float x1[8], y1[8], x2[8], y2[8], ha[8], ps[8];
#pragma unroll
    for (int q = 0; q < CPW; ++q) {
#pragma unroll
        for (int s = 0; s < 2; ++s) {
            const int k = q * 2 + s;
            const int c = CPW * wid + q;
            int idx = c * 128 + s * 64 + lane;
            float4 bb = boxes[base + idx];
            x1[k] = bb.x; y1[k] = bb.y; x2[k] = bb.z; y2[k] = bb.w;
            ps[k] = keys[base + idx];
            ha[k] = 0.5f * ((x2[k] - x1[k] + 1.f) * (y2[k] - y1[k] + 1.f));
        }
    }

    // step 1: per-cluster valid bbox + min area
#pragma unroll
    for (int q = 0; q < CPW; ++q) {
        const int k0 = 2 * q, k1 = 2 * q + 1;
        float mx = INFINITY, my = INFINITY, Mx = -INFINITY, My = -INFINITY, mA = INFINITY;
        if (ps[k0] != -INFINITY) { mx = x1[k0]; my = y1[k0]; Mx = x2[k0]; My = y2[k0]; mA = 2.f * ha[k0]; }
        if (ps[k1] != -INFINITY) { mx = fminf(mx, x1[k1]); my = fminf(my, y1[k1]);
                                   Mx = fmaxf(Mx, x2[k1]); My = fmaxf(My, y2[k1]);
                                   mA = fminf(mA, 2.f * ha[k1]); }
        mx = wave_fold_min(mx); my = wave_fold_min(my);
        Mx = wave_fold_max(Mx); My = wave_fold_max(My);
        mA = wave_fold_min(mA);
        if (lane == 63) {
            clusterBB[CPW * wid + q] = make_float4(mx, my, Mx, My);
            clusterMinA[CPW * wid + q] = mA;
        }
    }
    __syncthreads();

    // step 2 (wave 0): conservative cluster adjacency + state init
    if (wid == 0) {
        const int t = lane;
        float4 bbT = clusterBB[t];
        float  maT = clusterMinA[t];
        unsigned long long adj = 0ull;
        for (int j = 0; j < MM; ++j) {
            float4 bbJ = clusterBB[j];
            float  maJ = clusterMinA[j];
            float iw = fminf(bbT.z, bbJ.z) - fmaxf(bbT.x, bbJ.x) + 1.f;
            float ih = fminf(bbT.w, bbJ.w) - fmaxf(bbT.y, bbJ.y) + 1.f;
            if (j != t && iw > 0.f && ih > 0.f) {
                float I = iw * ih;
                // IoU>0.5 between members impossible if 3I < aI+aJ or 2I < max(aI,aJ)
                bool noe = (3.f * I < maT + maJ) || (2.f * I < fmaxf(maT, maJ));
                if (!noe) adj |= (1ull << j);
            }
        }
        adjL[t] = adj;
        keptCnt[0][t] = 0;
        changedL[0][t] = 1;
        if (t == 0) anyChange[0] = 1;
    }
    __syncthreads();

    // step 3: Jacobi rounds to fixed point
    int p = 0;
    for (int rr = 0; rr < 8200; ++rr) {
        if (anyChange[p] == 0) break;            // uniform exit
        if (tid == 0) anyChange[p ^ 1] = 0;
        __syncthreads();                          // B1
        int waveDiff = 0;
#pragma unroll
        for (int q = 0; q < CPW; ++q) {
            const int c = CPW * wid + q;
            const int np = p ^ 1;
            unsigned long long am = adjL[c];
            int needR = changedL[p][c];
            {
                unsigned long long m = am;
                while (m) { int ac = __ffsll(m) - 1; m &= (m - 1);
                            needR |= changedL[p][ac]; }
            }
            if (needR) {
                float a0 = ps[2 * q], a1 = ps[2 * q + 1];
                // premark: externally-kept higher-score boxes kill mine
                unsigned long long m = am;
                while (m) {
                    int ac = __ffsll(m) - 1; m &= (m - 1);
                    int K = keptCnt[p][ac];
                    for (int t2 = 0; t2 < K; ++t2) {
                        int gi = ac * 128 + keptIdx[p][ac][t2];
                        float sj = keys[base + gi];
                        float4 bj = boxes[base + gi];
                        float hbj = 0.5f * ((bj.z - bj.x + 1.f) * (bj.w - bj.y + 1.f))
                                    + 0.5f * EPS_F;
                        {
                            const int k = 2 * q;
                            float xx1 = fmaxf(bj.x, x1[k]), yy1 = fmaxf(bj.y, y1[k]);
                            float xx2 = fminf(bj.z, x2[k]), yy2 = fminf(bj.w, y2[k]);
                            float iw = fmaxf(xx2 - xx1 + 1.f, 0.f);
                            float ih = fmaxf(yy2 - yy1 + 1.f, 0.f);
                            float in2 = iw * ih;
                            if (sj > ps[k] && 1.5f * in2 > hbj + ha[k]) a0 = -INFINITY;
                        }
                        {
                            const int k = 2 * q + 1;
                            float xx1 = fmaxf(bj.x, x1[k]), yy1 = fmaxf(bj.y, y1[k]);
                            float xx2 = fminf(bj.z, x2[k]), yy2 = fminf(bj.w, y2[k]);
                            float iw = fmaxf(xx2 - xx1 + 1.f, 0.f);
                            float ih = fmaxf(yy2 - yy1 + 1.f, 0.f);
                            float in2 = iw * ih;
                            if (sj > ps[k] && 1.5f * in2 > hbj + ha[k]) a1 = -INFINITY;
                        }
                    }
                }
                // local serial greedy (wave-local, no barriers)
                int cnt = 0;
                while (true) {
                    float lv = fmaxf(a0, a1);
                    float wm = wave_max64(lv);
                    if (wm == -INFINITY) break;
                    unsigned long long bm = __ballot(lv == wm);
                    int wl = __ffsll(bm) - 1;
                    int la = (a0 == lv) ? 0 : 1;
                    float cxa = la ? x1[2 * q + 1] : x1[2 * q];
                    float cya = la ? y1[2 * q + 1] : y1[2 * q];
                    float cxb = la ? x2[2 * q + 1] : x2[2 * q];
                    float cyb = la ? y2[2 * q + 1] : y2[2 * q];
                    float cha = la ? ha[2 * q + 1] : ha[2 * q];
                    float bx1 = __shfl(cxa, wl), by1 = __shfl(cya, wl);
                    float bx2 = __shfl(cxb, wl), by2 = __shfl(cyb, wl);
                    float hcb = __shfl(cha, wl) + 0.5f * EPS_F;
                    if (lane == wl) {
                        keptIdx[np][c][cnt] = (short)(la * 64 + lane);
                        if (la == 0) a0 = -INFINITY; else a1 = -INFINITY;
                    }
                    cnt++;
                    if (a0 != -INFINITY) {
                        const int k = 2 * q;
                        float xx1 = fmaxf(bx1, x1[k]), yy1 = fmaxf(by1, y1[k]);
                        float xx2 = fminf(bx2, x2[k]), yy2 = fminf(by2, y2[k]);
                        float iw = fmaxf(xx2 - xx1 + 1.f, 0.f);
                        float ih = fmaxf(yy2 - yy1 + 1.f, 0.f);
                        if (1.5f * (iw * ih) > hcb + ha[k]) a0 = -INFINITY;
                    }
                    if (a1 != -INFINITY) {
                        const int k = 2 * q + 1;
                        float xx1 = fmaxf(bx1, x1[k]), yy1 = fmaxf(by1, y1[k]);
                        float xx2 = fminf(bx2, x2[k]), yy2 = fminf(by2, y2[k]);
                        float iw = fmaxf(xx2 - xx1 + 1.f, 0.f);
                        float ih = fmaxf(yy2 - yy1 + 1.f, 0.f);
                        if (1.5f * (iw * ih) > hcb + ha[k]) a1 = -INFINITY;
                    }
                }
                if (lane == 0) keptCnt[np][c] = cnt;
                // change detection
                int oldK = keptCnt[p][c];
                int diff = (cnt != oldK) ? 1 : 0;
                {
                    short na = (lane < cnt)  ? keptIdx[np][c][lane] : (short)-1;
                    short oa = (lane < oldK) ? keptIdx[p][c][lane]  : (short)-1;
                    diff |= (na != oa) ? 1 : 0;
                    int l2 = lane + 64;
                    short nb = (l2 < cnt)  ? keptIdx[np][c][l2] : (short)-1;
                    short ob = (l2 < oldK) ? keptIdx[p][c][l2]  : (short)-1;
                    diff |= (nb != ob) ? 1 : 0;
                }
                diff = (__ballot(diff != 0) != 0ull) ? 1 : 0;
                if (lane == 0) changedL[np][c] = diff;
                waveDiff |= diff;
            } else {
                int K = keptCnt[p][c];
                for (int t2 = lane; t2 < K; t2 += 64)
                    keptIdx[np][c][t2] = keptIdx[p][c][t2];
                if (lane == 0) { keptCnt[np][c] = K; changedL[np][c] = 0; }
            }
        }
        if (lane == 0 && waveDiff) atomicOr(&anyChange[p ^ 1], 1);
        __syncthreads();                          // B2
        p ^= 1;
    }

    // step 4: loss = sum(kept scores)/count
    float s = 0.f; int ccount = 0;
#pragma unroll
    for (int q = 0; q < CPW; ++q) {
        const int c = CPW * wid + q;
        int K = keptCnt[p][c];
        for (int t2 = lane; t2 < K; t2 += 64) {
            int gi = c * 128 + keptIdx[p][c][t2];
            s += keys[base + gi];
        }
        ccount += K;
    }
    s = wave_sum64(s);
    if (lane == 0) { waveSum[wid] = s; waveCnt[wid] = ccount; }
    __syncthreads();
    if (tid == 0) {
        float tot = 0.f; int ct = 0;
#pragma unroll
        for (int w = 0; w < NW; ++w) { tot += waveSum[w]; ct += waveCnt[w]; }
        loss[b] = tot / (float)ct;               // 0/0 -> NaN matches reference
    }
}

extern "C" void kernel_launch(void* const* d_in, const int* in_sizes, int n_in,
                              void* d_out, int out_size, void* d_ws, size_t ws_size,
                              hipStream_t stream) {
    const float* outp = (const float*)d_in[0];   // (B, N, 85) f32
    const float* lab  = (const float*)d_in[1];   // (B, M, 5)  f32
    float* loss = (float*)d_out;                 // (1, B) f32

    float4* boxes = (float4*)d_ws;                                    // 2 MB
    float*  keys  = (float*)((char*)d_ws + (size_t)BB * NN * sizeof(float4));

    dim3 g1(BB, NN / NT1);
    prep_kernel<<<g1, NT1, 0, stream>>>(outp, lab, boxes, keys);
    nms_kernel<<<BB, NT2, 0, stream>>>(boxes, keys, loss);
}